// Round 1
// 881.977 us; speedup vs baseline: 1.1651x; 1.1651x over previous
//
#include <hip/hip_runtime.h>
#include <hip/hip_bf16.h>
#include <math.h>

// Problem constants
#define Bn   32
#define Hh   56
#define Wd   56
#define Cc   192
#define NHh  6
#define HDim 32
#define HIDN 768
#define Tt   (Bn*Hh*Wd)          // 100352 tokens
#define NWIN (Bn*64)             // 2048 windows

typedef __attribute__((ext_vector_type(8))) short short8;
typedef __attribute__((ext_vector_type(4))) float floatx4;

__device__ __forceinline__ short f2bf(float f) {
    unsigned u = __float_as_uint(f);
    u += 0x7fffu + ((u >> 16) & 1u);     // round-to-nearest-even
    return (short)(u >> 16);
}
__device__ __forceinline__ float bf2f(short s) {
    return __uint_as_float(((unsigned)(unsigned short)s) << 16);
}

// ---------------------------------------------------------------------------
// Weight transpose + bf16 convert: W[K,N] fp32 -> WT[N,K] bf16
// ---------------------------------------------------------------------------
__global__ void k_transpose(const float* __restrict__ W, short* __restrict__ WT,
                            int K, int N) {
    int idx = blockIdx.x * 256 + threadIdx.x;
    if (idx >= K * N) return;
    int n = idx / K, k = idx % K;        // coalesced writes
    WT[idx] = f2bf(W[k * N + n]);
}

// ---------------------------------------------------------------------------
// QKV weight transpose with COLUMN PERMUTATION:
// reference column order is (d k h): col = d*18 + k*6 + h.
// We emit new order col' = k*192 + h*32 + d so the GEMM writes qkvbuf in a
// per-(k,head) contiguous-d layout -> attention loads become coalesced 64B rows.
// ---------------------------------------------------------------------------
__global__ void k_transpose_qkv(const float* __restrict__ W, short* __restrict__ WT) {
    int idx = blockIdx.x * 256 + threadIdx.x;
    if (idx >= 192 * 576) return;
    int n = idx / 192, kk = idx % 192;           // n = new col, kk = K row
    int d = n & 31, hh = (n >> 5) % 6, k3 = n / 192;
    int oc = d * 18 + k3 * 6 + hh;               // original column
    WT[idx] = f2bf(W[kk * 576 + oc]);
}

// ---------------------------------------------------------------------------
// Fused depthwise-3x3 CPE (residual) + LayerNorm. 8 tokens per block.
// ---------------------------------------------------------------------------
#define CPE_TPB 8
__global__ void __launch_bounds__(192) k_cpe_ln(
    const float* __restrict__ xin, const float* __restrict__ wconv,
    const float* __restrict__ bconv, const float* __restrict__ g,
    const float* __restrict__ beta, float* __restrict__ ysum_out,
    short* __restrict__ ln_out, int windowed)
{
    int c = threadIdx.x;
    __shared__ float wl[Cc * 9];
    __shared__ float red[6];
    for (int i = c; i < Cc * 9; i += 192) wl[i] = wconv[i];
    float bcv = bconv[c], gc = g[c], bc = beta[c];
    __syncthreads();

    int t0 = blockIdx.x * CPE_TPB;
    for (int tk = 0; tk < CPE_TPB; ++tk) {
        int blk = t0 + tk;
        int b = blk / (Hh * Wd);
        int rem = blk % (Hh * Wd);
        int h = rem / Wd, w = rem % Wd;

        float s = bcv;
        #pragma unroll
        for (int ky = 0; ky < 3; ++ky) {
            int hy = h + ky - 1;
            if (hy < 0 || hy >= Hh) continue;
            #pragma unroll
            for (int kx = 0; kx < 3; ++kx) {
                int wx = w + kx - 1;
                if (wx < 0 || wx >= Wd) continue;
                s += wl[c * 9 + ky * 3 + kx] *
                     xin[((size_t)b * (Hh * Wd) + hy * Wd + wx) * Cc + c];
            }
        }
        float val = xin[(size_t)blk * Cc + c] + s;
        ysum_out[(size_t)blk * Cc + c] = val;

        float p = val, p2 = val * val;
        #pragma unroll
        for (int off = 32; off; off >>= 1) {
            p  += __shfl_xor(p,  off, 64);
            p2 += __shfl_xor(p2, off, 64);
        }
        int wid = c >> 6;
        if ((c & 63) == 0) { red[wid * 2] = p; red[wid * 2 + 1] = p2; }
        __syncthreads();
        float sum  = red[0] + red[2] + red[4];
        float sum2 = red[1] + red[3] + red[5];
        __syncthreads();
        float mean = sum * (1.0f / Cc);
        float var  = sum2 * (1.0f / Cc) - mean * mean;
        float nrm  = (val - mean) * rsqrtf(var + 1e-5f) * gc + bc;

        int r;
        if (windowed) {
            int win = b * 64 + (h & 7) * 8 + (w & 7);
            int pos = (h >> 3) * 7 + (w >> 3);
            r = win * 49 + pos;
        } else {
            r = blk;
        }
        ln_out[(size_t)r * Cc + c] = f2bf(nrm);
    }
}

// ---------------------------------------------------------------------------
// Tiled MFMA GEMM (m93-style): BM=128, BN=64, BK=32, 256 thr / 4 waves.
// EPI==0: qkv output (bf16, permuted-column bias remap)
// EPI==1: proj output un-windowed, += into fp32 shortcut
// EPI==2: fc1 + exact GELU, bf16
// EPI==3: fc2, += into fp32 out
// ---------------------------------------------------------------------------
template<int K, int EPI>
__global__ void __launch_bounds__(256) k_gemm_tiled(
    const short* __restrict__ A, const short* __restrict__ BT,
    const float* __restrict__ bias, void* __restrict__ outp)
{
    __shared__ __align__(16) short As[128 * 32];
    __shared__ __align__(16) short Bs[64 * 32];
    const int tid = threadIdx.x;
    const int n0 = blockIdx.x * 64;
    const int m0 = blockIdx.y * 128;
    const int w = tid >> 6, lane = tid & 63;
    const int lcol = lane & 15, quad = lane >> 4;

    floatx4 acc[2][4];
    #pragma unroll
    for (int mi = 0; mi < 2; ++mi)
        #pragma unroll
        for (int ni = 0; ni < 4; ++ni) acc[mi][ni] = (floatx4){0, 0, 0, 0};

    const int ar = tid >> 2, ac = (tid & 3) * 8;
    const short* agp  = A + (size_t)(m0 + ar) * K + ac;
    const short* agp2 = A + (size_t)(m0 + 64 + ar) * K + ac;
    const short* bgp  = BT + (size_t)(n0 + ar) * K + ac;
    short* asw = As + tid * 8;
    short* bsw = Bs + tid * 8;

    const short* ard0 = As + (w * 32 + lcol) * 32 + quad * 8;
    const short* ard1 = As + (w * 32 + 16 + lcol) * 32 + quad * 8;
    const short* brd  = Bs + lcol * 32 + quad * 8;

    for (int k0 = 0; k0 < K; k0 += 32) {
        __syncthreads();
        short8 va0 = *(const short8*)(agp + k0);
        short8 va1 = *(const short8*)(agp2 + k0);
        short8 vb  = *(const short8*)(bgp + k0);
        *(short8*)asw             = va0;
        *(short8*)(asw + 64 * 32) = va1;
        *(short8*)bsw             = vb;
        __syncthreads();
        short8 a0 = *(const short8*)ard0;
        short8 a1 = *(const short8*)ard1;
        #pragma unroll
        for (int ni = 0; ni < 4; ++ni) {
            short8 b = *(const short8*)(brd + ni * 16 * 32);
            acc[0][ni] = __builtin_amdgcn_mfma_f32_16x16x32_bf16(a0, b, acc[0][ni], 0, 0, 0);
            acc[1][ni] = __builtin_amdgcn_mfma_f32_16x16x32_bf16(a1, b, acc[1][ni], 0, 0, 0);
        }
    }

    #pragma unroll
    for (int mi = 0; mi < 2; ++mi) {
        #pragma unroll
        for (int ni = 0; ni < 4; ++ni) {
            int col = n0 + ni * 16 + lcol;
            float bv;
            if (EPI == 0) {
                // permuted-column layout: col = k*192 + h*32 + d
                int d = col & 31, hh = (col >> 5) % 6, k3 = col / 192;
                bv = bias[d * 18 + k3 * 6 + hh];
            } else {
                bv = bias[col];
            }
            #pragma unroll
            for (int t = 0; t < 4; ++t) {
                int row = m0 + w * 32 + mi * 16 + quad * 4 + t;
                float v = acc[mi][ni][t] + bv;
                if (EPI == 0) {
                    ((short*)outp)[(size_t)row * 576 + col] = f2bf(v);
                } else if (EPI == 1) {
                    int win = row / 49, p = row % 49;
                    int b = win >> 6, wm = (win >> 3) & 7, wwm = win & 7;
                    int hh = (p / 7) * 8 + wm, ww = (p % 7) * 8 + wwm;
                    ((float*)outp)[((size_t)b * (Hh * Wd) + hh * Wd + ww) * Cc + col] += v;
                } else if (EPI == 2) {
                    float gl = 0.5f * v * (1.0f + erff(v * 0.70710678118654752f));
                    ((short*)outp)[(size_t)row * HIDN + col] = f2bf(gl);
                } else {
                    ((float*)outp)[(size_t)row * Cc + col] += v;
                }
            }
        }
    }
}

// ---------------------------------------------------------------------------
// MFMA window attention: one wave (64 thr) per (window, head).
// qkvbuf column layout is now [k*192 + h*32 + d] -> Q/K/V rows for a given
// (k,h) are 32 consecutive shorts (64B, 64B-aligned). Staging loads are
// short8, fully coalesced; every HBM byte is fetched exactly once chip-wide.
// LDS overlay: P reuses dead Q/K region (wave-local LDS is in-order).
// ---------------------------------------------------------------------------
__global__ void __launch_bounds__(64) k_attn(
    const short* __restrict__ C, short* __restrict__ aout)
{
    int h = blockIdx.x, win = blockIdx.y;
    int lane = threadIdx.x;
    int lcol = lane & 15, quad = lane >> 4;
    __shared__ __align__(16) short buf[7424];
    short* Q  = buf;            // [64*40]
    short* Kb = buf + 2560;     // [64*40]
    short* Vt = buf + 5120;     // [32*72]
    short* P  = buf;            // [64*72] overlays Q+Kb after S-phase

    const short8 z8 = {0, 0, 0, 0, 0, 0, 0, 0};
    const size_t wbase = (size_t)win * 49 * 576;
    const int hq = h * 32;
    const int pr = lane >> 2, d8 = (lane & 3) * 8;

    // Q and K: 16 rows per wave-iteration, 64B contiguous per row
    #pragma unroll
    for (int it = 0; it < 4; ++it) {
        int pp = pr + it * 16;
        bool ok = pp < 49;
        size_t ro = wbase + (size_t)(ok ? pp : 0) * 576 + hq + d8;
        short8 vq = ok ? *(const short8*)(C + ro)       : z8;
        short8 vk = ok ? *(const short8*)(C + ro + 192) : z8;
        *(short8*)(Q  + pp * 40 + d8) = vq;
        *(short8*)(Kb + pp * 40 + d8) = vk;
    }
    // V: coalesced row loads, transposed scatter into Vt[d][p]
    #pragma unroll
    for (int it = 0; it < 4; ++it) {
        int pp = pr + it * 16;
        bool ok = pp < 49;
        size_t ro = wbase + (size_t)(ok ? pp : 0) * 576 + 384 + hq + d8;
        short8 vv = ok ? *(const short8*)(C + ro) : z8;
        #pragma unroll
        for (int j = 0; j < 8; ++j)
            Vt[(d8 + j) * 72 + pp] = vv[j];
    }

    floatx4 s[4][4];
    #pragma unroll
    for (int mi = 0; mi < 4; ++mi) {
        short8 aq = *(const short8*)(Q + (mi * 16 + lcol) * 40 + quad * 8);
        #pragma unroll
        for (int ni = 0; ni < 4; ++ni) {
            short8 bk = *(const short8*)(Kb + (ni * 16 + lcol) * 40 + quad * 8);
            floatx4 z = {0, 0, 0, 0};
            s[mi][ni] = __builtin_amdgcn_mfma_f32_16x16x32_bf16(aq, bk, z, 0, 0, 0);
        }
    }

    const float scale = 0.17677669529663688f;   // 1/sqrt(32)
    #pragma unroll
    for (int mi = 0; mi < 4; ++mi) {
        #pragma unroll
        for (int reg = 0; reg < 4; ++reg) {
            float vv[4];
            float mx = -3e38f;
            #pragma unroll
            for (int ni = 0; ni < 4; ++ni) {
                int col = ni * 16 + lcol;
                float v = (col < 49) ? s[mi][ni][reg] * scale : -3e38f;
                vv[ni] = v;
                mx = fmaxf(mx, v);
            }
            #pragma unroll
            for (int off = 1; off < 16; off <<= 1)
                mx = fmaxf(mx, __shfl_xor(mx, off, 64));
            float sum = 0.f;
            #pragma unroll
            for (int ni = 0; ni < 4; ++ni) {
                int col = ni * 16 + lcol;
                float e = (col < 49) ? __expf(vv[ni] - mx) : 0.f;
                vv[ni] = e;
                sum += e;
            }
            #pragma unroll
            for (int off = 1; off < 16; off <<= 1)
                sum += __shfl_xor(sum, off, 64);
            float inv = 1.0f / sum;
            int row = mi * 16 + quad * 4 + reg;
            #pragma unroll
            for (int ni = 0; ni < 4; ++ni)
                P[row * 72 + ni * 16 + lcol] = f2bf(vv[ni] * inv);
        }
    }

    #pragma unroll
    for (int mi = 0; mi < 4; ++mi) {
        short8 a0 = *(const short8*)(P + (mi * 16 + lcol) * 72 + quad * 8);
        short8 a1 = *(const short8*)(P + (mi * 16 + lcol) * 72 + 32 + quad * 8);
        #pragma unroll
        for (int nd = 0; nd < 2; ++nd) {
            short8 b0 = *(const short8*)(Vt + (nd * 16 + lcol) * 72 + quad * 8);
            short8 b1 = *(const short8*)(Vt + (nd * 16 + lcol) * 72 + 32 + quad * 8);
            floatx4 z = {0, 0, 0, 0};
            floatx4 o = __builtin_amdgcn_mfma_f32_16x16x32_bf16(a0, b0, z, 0, 0, 0);
            o = __builtin_amdgcn_mfma_f32_16x16x32_bf16(a1, b1, o, 0, 0, 0);
            #pragma unroll
            for (int reg = 0; reg < 4; ++reg) {
                int row = mi * 16 + quad * 4 + reg;
                if (row < 49)
                    aout[((size_t)win * 49 + row) * Cc + h * HDim + nd * 16 + lcol] =
                        f2bf(o[reg]);
            }
        }
    }
}

// ---------------------------------------------------------------------------
extern "C" void kernel_launch(void* const* d_in, const int* in_sizes, int n_in,
                              void* d_out, int out_size, void* d_ws, size_t ws_size,
                              hipStream_t stream)
{
    (void)in_sizes; (void)n_in; (void)out_size; (void)ws_size;
    const float* x      = (const float*)d_in[0];
    const float* cpe0_w = (const float*)d_in[3];
    const float* cpe0_b = (const float*)d_in[4];
    const float* cpe1_w = (const float*)d_in[5];
    const float* cpe1_b = (const float*)d_in[6];
    const float* n1_g   = (const float*)d_in[7];
    const float* n1_b   = (const float*)d_in[8];
    const float* qkv_w  = (const float*)d_in[9];
    const float* qkv_b  = (const float*)d_in[10];
    const float* proj_w = (const float*)d_in[11];
    const float* proj_b = (const float*)d_in[12];
    const float* n2_g   = (const float*)d_in[13];
    const float* n2_b   = (const float*)d_in[14];
    const float* fc1_w  = (const float*)d_in[15];
    const float* fc1_b  = (const float*)d_in[16];
    const float* fc2_w  = (const float*)d_in[17];
    const float* fc2_b  = (const float*)d_in[18];
    float* out = (float*)d_out;

    char* ws = (char*)d_ws;
    float* shortcut = (float*)ws;                     // 77,070,336  (fp32 Tt*192)
    short* lnbuf    = (short*)(ws + 77070336);        // 38,535,168  (bf16 Tt*192)
    short* qkvbuf   = (short*)(ws + 115605504);       // 115,605,504 (bf16 Tt*576)
    short* attnout  = (short*)(ws + 231211008);       // 38,535,168
    short* h1       = qkvbuf;                         // overlays qkv+attn
    short* wqkvT    = (short*)(ws + 269746176);       // 221,184
    short* wprojT   = (short*)(ws + 269967360);       // 73,728
    short* wfc1T    = (short*)(ws + 270041088);       // 294,912
    short* wfc2T    = (short*)(ws + 270336000);       // 294,912

    k_transpose_qkv<<<dim3((192 * 576 + 255) / 256), dim3(256), 0, stream>>>(qkv_w, wqkvT);
    k_transpose<<<dim3((192 * 192 + 255) / 256), dim3(256), 0, stream>>>(proj_w, wprojT, 192, 192);
    k_transpose<<<dim3((192 * 768 + 255) / 256), dim3(256), 0, stream>>>(fc1_w, wfc1T, 192, 768);
    k_transpose<<<dim3((768 * 192 + 255) / 256), dim3(256), 0, stream>>>(fc2_w, wfc2T, 768, 192);

    k_cpe_ln<<<dim3(Tt / CPE_TPB), dim3(192), 0, stream>>>(x, cpe0_w, cpe0_b, n1_g, n1_b,
                                                           shortcut, lnbuf, 1);
    k_gemm_tiled<192, 0><<<dim3(9, Tt / 128), dim3(256), 0, stream>>>(lnbuf, wqkvT, qkv_b, qkvbuf);
    k_attn<<<dim3(NHh, NWIN), dim3(64), 0, stream>>>(qkvbuf, attnout);
    k_gemm_tiled<192, 1><<<dim3(3, Tt / 128), dim3(256), 0, stream>>>(attnout, wprojT, proj_b, shortcut);
    k_cpe_ln<<<dim3(Tt / CPE_TPB), dim3(192), 0, stream>>>(shortcut, cpe1_w, cpe1_b, n2_g, n2_b,
                                                           out, lnbuf, 0);
    k_gemm_tiled<192, 2><<<dim3(12, Tt / 128), dim3(256), 0, stream>>>(lnbuf, wfc1T, fc1_b, h1);
    k_gemm_tiled<768, 3><<<dim3(3, Tt / 128), dim3(256), 0, stream>>>(h1, wfc2T, fc2_b, out);
}

// Round 2
// 786.098 us; speedup vs baseline: 1.3072x; 1.1220x over previous
//
#include <hip/hip_runtime.h>
#include <hip/hip_bf16.h>
#include <math.h>

// Problem constants
#define Bn   32
#define Hh   56
#define Wd   56
#define Cc   192
#define NHh  6
#define HDim 32
#define HIDN 768
#define Tt   (Bn*Hh*Wd)          // 100352 tokens
#define NWIN (Bn*64)             // 2048 windows

typedef __attribute__((ext_vector_type(8))) short short8;
typedef __attribute__((ext_vector_type(4))) short s4v;
typedef __attribute__((ext_vector_type(4))) float floatx4;

__device__ __forceinline__ short f2bf(float f) {
    unsigned u = __float_as_uint(f);
    u += 0x7fffu + ((u >> 16) & 1u);     // round-to-nearest-even
    return (short)(u >> 16);
}
__device__ __forceinline__ float bf2f(short s) {
    return __uint_as_float(((unsigned)(unsigned short)s) << 16);
}

// ---------------------------------------------------------------------------
// Weight transpose + bf16 convert: W[K,N] fp32 -> WT[N,K] bf16
// ---------------------------------------------------------------------------
__global__ void k_transpose(const float* __restrict__ W, short* __restrict__ WT,
                            int K, int N) {
    int idx = blockIdx.x * 256 + threadIdx.x;
    if (idx >= K * N) return;
    int n = idx / K, k = idx % K;        // coalesced writes
    WT[idx] = f2bf(W[k * N + n]);
}

// ---------------------------------------------------------------------------
// QKV weight transpose with COLUMN PERMUTATION:
// reference column order is (d k h): col = d*18 + k*6 + h.
// We emit new order col' = k*192 + h*32 + d so the GEMM writes qkvbuf in a
// per-(k,head) contiguous-d layout -> attention loads become coalesced 64B rows.
// ---------------------------------------------------------------------------
__global__ void k_transpose_qkv(const float* __restrict__ W, short* __restrict__ WT) {
    int idx = blockIdx.x * 256 + threadIdx.x;
    if (idx >= 192 * 576) return;
    int n = idx / 192, kk = idx % 192;           // n = new col, kk = K row
    int d = n & 31, hh = (n >> 5) % 6, k3 = n / 192;
    int oc = d * 18 + k3 * 6 + hh;               // original column
    WT[idx] = f2bf(W[kk * 576 + oc]);
}

// ---------------------------------------------------------------------------
// Fused depthwise-3x3 CPE (residual) + LayerNorm.
// Wave-per-token: lane<48 owns 4 channels (float4). Conv weights (36 f),
// gamma/beta/bias in registers. LN reduce = 6-step shfl_xor. ZERO barriers.
// 4 waves/block x CPE_TPW tokens per wave.
// ---------------------------------------------------------------------------
#define CPE_TPW 8
__global__ void __launch_bounds__(256) k_cpe_ln(
    const float* __restrict__ xin, const float* __restrict__ wconv,
    const float* __restrict__ bconv, const float* __restrict__ g,
    const float* __restrict__ beta, float* __restrict__ ysum_out,
    short* __restrict__ ln_out, int windowed)
{
    const int lane = threadIdx.x & 63;
    const int wv   = threadIdx.x >> 6;
    const bool act = lane < 48;
    const int c4   = lane * 4;           // channel base (valid when act)

    const floatx4 zf = {0.f, 0.f, 0.f, 0.f};
    float wreg[36];
    floatx4 gv = zf, bv = zf, bcv = zf;
    if (act) {
        #pragma unroll
        for (int i = 0; i < 9; ++i)
            *(floatx4*)&wreg[i * 4] = *(const floatx4*)(wconv + c4 * 9 + i * 4);
        gv  = *(const floatx4*)(g + c4);
        bv  = *(const floatx4*)(beta + c4);
        bcv = *(const floatx4*)(bconv + c4);
    } else {
        #pragma unroll
        for (int i = 0; i < 36; ++i) wreg[i] = 0.f;
    }

    const int t0 = (blockIdx.x * 4 + wv) * CPE_TPW;
    for (int tk = 0; tk < CPE_TPW; ++tk) {
        const int blk = t0 + tk;
        const int b = blk / (Hh * Wd);
        const int rem = blk % (Hh * Wd);
        const int h = rem / Wd, w = rem % Wd;

        floatx4 acc = act ? bcv : zf;
        #pragma unroll
        for (int ky = 0; ky < 3; ++ky) {
            int hy = h + ky - 1;
            if (hy < 0 || hy >= Hh) continue;          // wave-uniform branch
            #pragma unroll
            for (int kx = 0; kx < 3; ++kx) {
                int wx = w + kx - 1;
                if (wx < 0 || wx >= Wd) continue;      // wave-uniform branch
                floatx4 v = act ? *(const floatx4*)(
                    xin + ((size_t)b * (Hh * Wd) + hy * Wd + wx) * Cc + c4) : zf;
                const int t = ky * 3 + kx;
                #pragma unroll
                for (int j = 0; j < 4; ++j)
                    acc[j] += wreg[j * 9 + t] * v[j];
            }
        }
        floatx4 xc = act ? *(const floatx4*)(xin + (size_t)blk * Cc + c4) : zf;
        floatx4 val;
        #pragma unroll
        for (int j = 0; j < 4; ++j) val[j] = xc[j] + acc[j];
        if (act)
            *(floatx4*)(ysum_out + (size_t)blk * Cc + c4) = val;

        float s  = val[0] + val[1] + val[2] + val[3];
        float s2 = val[0]*val[0] + val[1]*val[1] + val[2]*val[2] + val[3]*val[3];
        #pragma unroll
        for (int off = 1; off < 64; off <<= 1) {
            s  += __shfl_xor(s,  off, 64);
            s2 += __shfl_xor(s2, off, 64);
        }
        const float mean = s * (1.0f / Cc);
        const float var  = s2 * (1.0f / Cc) - mean * mean;
        const float rs   = rsqrtf(var + 1e-5f);

        int r;
        if (windowed) {
            int win = b * 64 + (h & 7) * 8 + (w & 7);
            int pos = (h >> 3) * 7 + (w >> 3);
            r = win * 49 + pos;
        } else {
            r = blk;
        }
        if (act) {
            s4v o;
            #pragma unroll
            for (int j = 0; j < 4; ++j)
                o[j] = f2bf((val[j] - mean) * rs * gv[j] + bv[j]);
            *(s4v*)(ln_out + (size_t)r * Cc + c4) = o;
        }
    }
}

// ---------------------------------------------------------------------------
// Tiled MFMA GEMM (m93-style): BM=128, BN=64, BK=32, 256 thr / 4 waves.
// EPI==0: qkv output (bf16, permuted-column bias remap)
// EPI==1: proj output un-windowed, += into fp32 shortcut
// EPI==2: fc1 + exact GELU, bf16
// EPI==3: fc2, += into fp32 out
// ---------------------------------------------------------------------------
template<int K, int EPI>
__global__ void __launch_bounds__(256) k_gemm_tiled(
    const short* __restrict__ A, const short* __restrict__ BT,
    const float* __restrict__ bias, void* __restrict__ outp)
{
    __shared__ __align__(16) short As[128 * 32];
    __shared__ __align__(16) short Bs[64 * 32];
    const int tid = threadIdx.x;
    const int n0 = blockIdx.x * 64;
    const int m0 = blockIdx.y * 128;
    const int w = tid >> 6, lane = tid & 63;
    const int lcol = lane & 15, quad = lane >> 4;

    floatx4 acc[2][4];
    #pragma unroll
    for (int mi = 0; mi < 2; ++mi)
        #pragma unroll
        for (int ni = 0; ni < 4; ++ni) acc[mi][ni] = (floatx4){0, 0, 0, 0};

    const int ar = tid >> 2, ac = (tid & 3) * 8;
    const short* agp  = A + (size_t)(m0 + ar) * K + ac;
    const short* agp2 = A + (size_t)(m0 + 64 + ar) * K + ac;
    const short* bgp  = BT + (size_t)(n0 + ar) * K + ac;
    short* asw = As + tid * 8;
    short* bsw = Bs + tid * 8;

    const short* ard0 = As + (w * 32 + lcol) * 32 + quad * 8;
    const short* ard1 = As + (w * 32 + 16 + lcol) * 32 + quad * 8;
    const short* brd  = Bs + lcol * 32 + quad * 8;

    for (int k0 = 0; k0 < K; k0 += 32) {
        __syncthreads();
        short8 va0 = *(const short8*)(agp + k0);
        short8 va1 = *(const short8*)(agp2 + k0);
        short8 vb  = *(const short8*)(bgp + k0);
        *(short8*)asw             = va0;
        *(short8*)(asw + 64 * 32) = va1;
        *(short8*)bsw             = vb;
        __syncthreads();
        short8 a0 = *(const short8*)ard0;
        short8 a1 = *(const short8*)ard1;
        #pragma unroll
        for (int ni = 0; ni < 4; ++ni) {
            short8 b = *(const short8*)(brd + ni * 16 * 32);
            acc[0][ni] = __builtin_amdgcn_mfma_f32_16x16x32_bf16(a0, b, acc[0][ni], 0, 0, 0);
            acc[1][ni] = __builtin_amdgcn_mfma_f32_16x16x32_bf16(a1, b, acc[1][ni], 0, 0, 0);
        }
    }

    #pragma unroll
    for (int mi = 0; mi < 2; ++mi) {
        #pragma unroll
        for (int ni = 0; ni < 4; ++ni) {
            int col = n0 + ni * 16 + lcol;
            float bv;
            if (EPI == 0) {
                // permuted-column layout: col = k*192 + h*32 + d
                int d = col & 31, hh = (col >> 5) % 6, k3 = col / 192;
                bv = bias[d * 18 + k3 * 6 + hh];
            } else {
                bv = bias[col];
            }
            #pragma unroll
            for (int t = 0; t < 4; ++t) {
                int row = m0 + w * 32 + mi * 16 + quad * 4 + t;
                float v = acc[mi][ni][t] + bv;
                if (EPI == 0) {
                    ((short*)outp)[(size_t)row * 576 + col] = f2bf(v);
                } else if (EPI == 1) {
                    int win = row / 49, p = row % 49;
                    int b = win >> 6, wm = (win >> 3) & 7, wwm = win & 7;
                    int hh = (p / 7) * 8 + wm, ww = (p % 7) * 8 + wwm;
                    ((float*)outp)[((size_t)b * (Hh * Wd) + hh * Wd + ww) * Cc + col] += v;
                } else if (EPI == 2) {
                    float gl = 0.5f * v * (1.0f + erff(v * 0.70710678118654752f));
                    ((short*)outp)[(size_t)row * HIDN + col] = f2bf(gl);
                } else {
                    ((float*)outp)[(size_t)row * Cc + col] += v;
                }
            }
        }
    }
}

// ---------------------------------------------------------------------------
// MFMA window attention: one wave (64 thr) per (window, head).
// qkvbuf column layout is [k*192 + h*32 + d] -> Q/K/V rows for a given
// (k,h) are 32 consecutive shorts (64B, 64B-aligned). Staging loads are
// short8, fully coalesced. LDS overlay: P reuses dead Q/K region.
// ---------------------------------------------------------------------------
__global__ void __launch_bounds__(64) k_attn(
    const short* __restrict__ C, short* __restrict__ aout)
{
    int h = blockIdx.x, win = blockIdx.y;
    int lane = threadIdx.x;
    int lcol = lane & 15, quad = lane >> 4;
    __shared__ __align__(16) short buf[7424];
    short* Q  = buf;            // [64*40]
    short* Kb = buf + 2560;     // [64*40]
    short* Vt = buf + 5120;     // [32*72]
    short* P  = buf;            // [64*72] overlays Q+Kb after S-phase

    const short8 z8 = {0, 0, 0, 0, 0, 0, 0, 0};
    const size_t wbase = (size_t)win * 49 * 576;
    const int hq = h * 32;
    const int pr = lane >> 2, d8 = (lane & 3) * 8;

    // Q and K: 16 rows per wave-iteration, 64B contiguous per row
    #pragma unroll
    for (int it = 0; it < 4; ++it) {
        int pp = pr + it * 16;
        bool ok = pp < 49;
        size_t ro = wbase + (size_t)(ok ? pp : 0) * 576 + hq + d8;
        short8 vq = ok ? *(const short8*)(C + ro)       : z8;
        short8 vk = ok ? *(const short8*)(C + ro + 192) : z8;
        *(short8*)(Q  + pp * 40 + d8) = vq;
        *(short8*)(Kb + pp * 40 + d8) = vk;
    }
    // V: coalesced row loads, transposed scatter into Vt[d][p]
    #pragma unroll
    for (int it = 0; it < 4; ++it) {
        int pp = pr + it * 16;
        bool ok = pp < 49;
        size_t ro = wbase + (size_t)(ok ? pp : 0) * 576 + 384 + hq + d8;
        short8 vv = ok ? *(const short8*)(C + ro) : z8;
        #pragma unroll
        for (int j = 0; j < 8; ++j)
            Vt[(d8 + j) * 72 + pp] = vv[j];
    }

    floatx4 s[4][4];
    #pragma unroll
    for (int mi = 0; mi < 4; ++mi) {
        short8 aq = *(const short8*)(Q + (mi * 16 + lcol) * 40 + quad * 8);
        #pragma unroll
        for (int ni = 0; ni < 4; ++ni) {
            short8 bk = *(const short8*)(Kb + (ni * 16 + lcol) * 40 + quad * 8);
            floatx4 z = {0, 0, 0, 0};
            s[mi][ni] = __builtin_amdgcn_mfma_f32_16x16x32_bf16(aq, bk, z, 0, 0, 0);
        }
    }

    const float scale = 0.17677669529663688f;   // 1/sqrt(32)
    #pragma unroll
    for (int mi = 0; mi < 4; ++mi) {
        #pragma unroll
        for (int reg = 0; reg < 4; ++reg) {
            float vv[4];
            float mx = -3e38f;
            #pragma unroll
            for (int ni = 0; ni < 4; ++ni) {
                int col = ni * 16 + lcol;
                float v = (col < 49) ? s[mi][ni][reg] * scale : -3e38f;
                vv[ni] = v;
                mx = fmaxf(mx, v);
            }
            #pragma unroll
            for (int off = 1; off < 16; off <<= 1)
                mx = fmaxf(mx, __shfl_xor(mx, off, 64));
            float sum = 0.f;
            #pragma unroll
            for (int ni = 0; ni < 4; ++ni) {
                int col = ni * 16 + lcol;
                float e = (col < 49) ? __expf(vv[ni] - mx) : 0.f;
                vv[ni] = e;
                sum += e;
            }
            #pragma unroll
            for (int off = 1; off < 16; off <<= 1)
                sum += __shfl_xor(sum, off, 64);
            float inv = 1.0f / sum;
            int row = mi * 16 + quad * 4 + reg;
            #pragma unroll
            for (int ni = 0; ni < 4; ++ni)
                P[row * 72 + ni * 16 + lcol] = f2bf(vv[ni] * inv);
        }
    }

    #pragma unroll
    for (int mi = 0; mi < 4; ++mi) {
        short8 a0 = *(const short8*)(P + (mi * 16 + lcol) * 72 + quad * 8);
        short8 a1 = *(const short8*)(P + (mi * 16 + lcol) * 72 + 32 + quad * 8);
        #pragma unroll
        for (int nd = 0; nd < 2; ++nd) {
            short8 b0 = *(const short8*)(Vt + (nd * 16 + lcol) * 72 + quad * 8);
            short8 b1 = *(const short8*)(Vt + (nd * 16 + lcol) * 72 + 32 + quad * 8);
            floatx4 z = {0, 0, 0, 0};
            floatx4 o = __builtin_amdgcn_mfma_f32_16x16x32_bf16(a0, b0, z, 0, 0, 0);
            o = __builtin_amdgcn_mfma_f32_16x16x32_bf16(a1, b1, o, 0, 0, 0);
            #pragma unroll
            for (int reg = 0; reg < 4; ++reg) {
                int row = mi * 16 + quad * 4 + reg;
                if (row < 49)
                    aout[((size_t)win * 49 + row) * Cc + h * HDim + nd * 16 + lcol] =
                        f2bf(o[reg]);
            }
        }
    }
}

// ---------------------------------------------------------------------------
extern "C" void kernel_launch(void* const* d_in, const int* in_sizes, int n_in,
                              void* d_out, int out_size, void* d_ws, size_t ws_size,
                              hipStream_t stream)
{
    (void)in_sizes; (void)n_in; (void)out_size; (void)ws_size;
    const float* x      = (const float*)d_in[0];
    const float* cpe0_w = (const float*)d_in[3];
    const float* cpe0_b = (const float*)d_in[4];
    const float* cpe1_w = (const float*)d_in[5];
    const float* cpe1_b = (const float*)d_in[6];
    const float* n1_g   = (const float*)d_in[7];
    const float* n1_b   = (const float*)d_in[8];
    const float* qkv_w  = (const float*)d_in[9];
    const float* qkv_b  = (const float*)d_in[10];
    const float* proj_w = (const float*)d_in[11];
    const float* proj_b = (const float*)d_in[12];
    const float* n2_g   = (const float*)d_in[13];
    const float* n2_b   = (const float*)d_in[14];
    const float* fc1_w  = (const float*)d_in[15];
    const float* fc1_b  = (const float*)d_in[16];
    const float* fc2_w  = (const float*)d_in[17];
    const float* fc2_b  = (const float*)d_in[18];
    float* out = (float*)d_out;

    char* ws = (char*)d_ws;
    float* shortcut = (float*)ws;                     // 77,070,336  (fp32 Tt*192)
    short* lnbuf    = (short*)(ws + 77070336);        // 38,535,168  (bf16 Tt*192)
    short* qkvbuf   = (short*)(ws + 115605504);       // 115,605,504 (bf16 Tt*576)
    short* attnout  = (short*)(ws + 231211008);       // 38,535,168
    short* h1       = qkvbuf;                         // overlays qkv+attn
    short* wqkvT    = (short*)(ws + 269746176);       // 221,184
    short* wprojT   = (short*)(ws + 269967360);       // 73,728
    short* wfc1T    = (short*)(ws + 270041088);       // 294,912
    short* wfc2T    = (short*)(ws + 270336000);       // 294,912

    k_transpose_qkv<<<dim3((192 * 576 + 255) / 256), dim3(256), 0, stream>>>(qkv_w, wqkvT);
    k_transpose<<<dim3((192 * 192 + 255) / 256), dim3(256), 0, stream>>>(proj_w, wprojT, 192, 192);
    k_transpose<<<dim3((192 * 768 + 255) / 256), dim3(256), 0, stream>>>(fc1_w, wfc1T, 192, 768);
    k_transpose<<<dim3((768 * 192 + 255) / 256), dim3(256), 0, stream>>>(fc2_w, wfc2T, 768, 192);

    k_cpe_ln<<<dim3(Tt / (4 * CPE_TPW)), dim3(256), 0, stream>>>(x, cpe0_w, cpe0_b, n1_g, n1_b,
                                                                 shortcut, lnbuf, 1);
    k_gemm_tiled<192, 0><<<dim3(9, Tt / 128), dim3(256), 0, stream>>>(lnbuf, wqkvT, qkv_b, qkvbuf);
    k_attn<<<dim3(NHh, NWIN), dim3(64), 0, stream>>>(qkvbuf, attnout);
    k_gemm_tiled<192, 1><<<dim3(3, Tt / 128), dim3(256), 0, stream>>>(attnout, wprojT, proj_b, shortcut);
    k_cpe_ln<<<dim3(Tt / (4 * CPE_TPW)), dim3(256), 0, stream>>>(shortcut, cpe1_w, cpe1_b, n2_g, n2_b,
                                                                 out, lnbuf, 0);
    k_gemm_tiled<192, 2><<<dim3(12, Tt / 128), dim3(256), 0, stream>>>(lnbuf, wfc1T, fc1_b, h1);
    k_gemm_tiled<768, 3><<<dim3(3, Tt / 128), dim3(256), 0, stream>>>(h1, wfc2T, fc2_b, out);
}

// Round 3
// 705.393 us; speedup vs baseline: 1.4568x; 1.1144x over previous
//
#include <hip/hip_runtime.h>
#include <hip/hip_bf16.h>
#include <math.h>

// Problem constants
#define Bn   32
#define Hh   56
#define Wd   56
#define Cc   192
#define NHh  6
#define HDim 32
#define HIDN 768
#define Tt   (Bn*Hh*Wd)          // 100352 tokens
#define NWIN (Bn*64)             // 2048 windows

typedef __attribute__((ext_vector_type(8))) short short8;
typedef __attribute__((ext_vector_type(4))) short s4v;
typedef __attribute__((ext_vector_type(4))) float floatx4;

__device__ __forceinline__ short f2bf(float f) {
    unsigned u = __float_as_uint(f);
    u += 0x7fffu + ((u >> 16) & 1u);     // round-to-nearest-even
    return (short)(u >> 16);
}
__device__ __forceinline__ float bf2f(short s) {
    return __uint_as_float(((unsigned)(unsigned short)s) << 16);
}

// XCD-aware bijective block swizzle (requires nb % 8 == 0): each XCD gets a
// contiguous chunk of the flat block range -> neighbor blocks share an L2.
__device__ __forceinline__ int xcd_swz(int bid, int nb) {
    return (bid & 7) * (nb >> 3) + (bid >> 3);
}

// ---------------------------------------------------------------------------
// Weight transpose + bf16 convert: W[K,N] fp32 -> WT[N,K] bf16
// ---------------------------------------------------------------------------
__global__ void k_transpose(const float* __restrict__ W, short* __restrict__ WT,
                            int K, int N) {
    int idx = blockIdx.x * 256 + threadIdx.x;
    if (idx >= K * N) return;
    int n = idx / K, k = idx % K;        // coalesced writes
    WT[idx] = f2bf(W[k * N + n]);
}

// ---------------------------------------------------------------------------
// QKV weight transpose with COLUMN PERMUTATION:
// reference column order is (d k h): col = d*18 + k*6 + h.
// We emit new order col' = k*192 + h*32 + d so the GEMM writes qkvbuf in a
// per-(k,head) contiguous-d layout -> attention loads become coalesced 64B rows.
// ---------------------------------------------------------------------------
__global__ void k_transpose_qkv(const float* __restrict__ W, short* __restrict__ WT) {
    int idx = blockIdx.x * 256 + threadIdx.x;
    if (idx >= 192 * 576) return;
    int n = idx / 192, kk = idx % 192;           // n = new col, kk = K row
    int d = n & 31, hh = (n >> 5) % 6, k3 = n / 192;
    int oc = d * 18 + k3 * 6 + hh;               // original column
    WT[idx] = f2bf(W[kk * 576 + oc]);
}

// ---------------------------------------------------------------------------
// Fused depthwise-3x3 CPE (residual) + LayerNorm.
// Wave-per-token: lane<48 owns 4 channels (float4). Conv weights (36 f),
// gamma/beta/bias in registers. LN reduce = 6-step shfl_xor. ZERO barriers.
// 4 waves/block x CPE_TPW tokens per wave. XCD-chunked block order so
// h-neighbor rows (stencil reuse) stay in the same per-XCD L2.
// ---------------------------------------------------------------------------
#define CPE_TPW 8
__global__ void __launch_bounds__(256) k_cpe_ln(
    const float* __restrict__ xin, const float* __restrict__ wconv,
    const float* __restrict__ bconv, const float* __restrict__ g,
    const float* __restrict__ beta, float* __restrict__ ysum_out,
    short* __restrict__ ln_out, int windowed)
{
    const int lane = threadIdx.x & 63;
    const int wv   = threadIdx.x >> 6;
    const bool act = lane < 48;
    const int c4   = lane * 4;           // channel base (valid when act)

    const floatx4 zf = {0.f, 0.f, 0.f, 0.f};
    float wreg[36];
    floatx4 gv = zf, bv = zf, bcv = zf;
    if (act) {
        #pragma unroll
        for (int i = 0; i < 9; ++i)
            *(floatx4*)&wreg[i * 4] = *(const floatx4*)(wconv + c4 * 9 + i * 4);
        gv  = *(const floatx4*)(g + c4);
        bv  = *(const floatx4*)(beta + c4);
        bcv = *(const floatx4*)(bconv + c4);
    } else {
        #pragma unroll
        for (int i = 0; i < 36; ++i) wreg[i] = 0.f;
    }

    const int sb = xcd_swz(blockIdx.x, gridDim.x);
    const int t0 = (sb * 4 + wv) * CPE_TPW;
    #pragma unroll 2
    for (int tk = 0; tk < CPE_TPW; ++tk) {
        const int blk = t0 + tk;
        const int b = blk / (Hh * Wd);
        const int rem = blk % (Hh * Wd);
        const int h = rem / Wd, w = rem % Wd;

        floatx4 acc = act ? bcv : zf;
        #pragma unroll
        for (int ky = 0; ky < 3; ++ky) {
            int hy = h + ky - 1;
            if (hy < 0 || hy >= Hh) continue;          // wave-uniform branch
            #pragma unroll
            for (int kx = 0; kx < 3; ++kx) {
                int wx = w + kx - 1;
                if (wx < 0 || wx >= Wd) continue;      // wave-uniform branch
                floatx4 v = act ? *(const floatx4*)(
                    xin + ((size_t)b * (Hh * Wd) + hy * Wd + wx) * Cc + c4) : zf;
                const int t = ky * 3 + kx;
                #pragma unroll
                for (int j = 0; j < 4; ++j)
                    acc[j] += wreg[j * 9 + t] * v[j];
            }
        }
        floatx4 xc = act ? *(const floatx4*)(xin + (size_t)blk * Cc + c4) : zf;
        floatx4 val;
        #pragma unroll
        for (int j = 0; j < 4; ++j) val[j] = xc[j] + acc[j];
        if (act)
            *(floatx4*)(ysum_out + (size_t)blk * Cc + c4) = val;

        float s  = val[0] + val[1] + val[2] + val[3];
        float s2 = val[0]*val[0] + val[1]*val[1] + val[2]*val[2] + val[3]*val[3];
        #pragma unroll
        for (int off = 1; off < 64; off <<= 1) {
            s  += __shfl_xor(s,  off, 64);
            s2 += __shfl_xor(s2, off, 64);
        }
        const float mean = s * (1.0f / Cc);
        const float var  = s2 * (1.0f / Cc) - mean * mean;
        const float rs   = rsqrtf(var + 1e-5f);

        int r;
        if (windowed) {
            int win = b * 64 + (h & 7) * 8 + (w & 7);
            int pos = (h >> 3) * 7 + (w >> 3);
            r = win * 49 + pos;
        } else {
            r = blk;
        }
        if (act) {
            s4v o;
            #pragma unroll
            for (int j = 0; j < 4; ++j)
                o[j] = f2bf((val[j] - mean) * rs * gv[j] + bv[j]);
            *(s4v*)(ln_out + (size_t)r * Cc + c4) = o;
        }
    }
}

// ---------------------------------------------------------------------------
// Tiled MFMA GEMM (m93-style): BM=128, BN=64, BK=32, 256 thr / 4 waves.
// XCD-chunked flat-block swizzle: the gx n-tiles sharing one A-panel stay on
// one XCD (A-panel L2 reuse).
// EPI==0: qkv output (bf16, permuted-column bias remap)
// EPI==1: proj output un-windowed, += into fp32 shortcut
// EPI==2: fc1 + exact GELU, bf16
// EPI==3: fc2, += into fp32 out
// ---------------------------------------------------------------------------
template<int K, int EPI>
__global__ void __launch_bounds__(256) k_gemm_tiled(
    const short* __restrict__ A, const short* __restrict__ BT,
    const float* __restrict__ bias, void* __restrict__ outp)
{
    __shared__ __align__(16) short As[128 * 32];
    __shared__ __align__(16) short Bs[64 * 32];
    const int tid = threadIdx.x;
    const int gx = gridDim.x;
    const int flat = blockIdx.y * gx + blockIdx.x;
    const int swz = xcd_swz(flat, gx * gridDim.y);
    const int n0 = (swz % gx) * 64;
    const int m0 = (swz / gx) * 128;
    const int w = tid >> 6, lane = tid & 63;
    const int lcol = lane & 15, quad = lane >> 4;

    floatx4 acc[2][4];
    #pragma unroll
    for (int mi = 0; mi < 2; ++mi)
        #pragma unroll
        for (int ni = 0; ni < 4; ++ni) acc[mi][ni] = (floatx4){0, 0, 0, 0};

    const int ar = tid >> 2, ac = (tid & 3) * 8;
    const short* agp  = A + (size_t)(m0 + ar) * K + ac;
    const short* agp2 = A + (size_t)(m0 + 64 + ar) * K + ac;
    const short* bgp  = BT + (size_t)(n0 + ar) * K + ac;
    short* asw = As + tid * 8;
    short* bsw = Bs + tid * 8;

    const short* ard0 = As + (w * 32 + lcol) * 32 + quad * 8;
    const short* ard1 = As + (w * 32 + 16 + lcol) * 32 + quad * 8;
    const short* brd  = Bs + lcol * 32 + quad * 8;

    for (int k0 = 0; k0 < K; k0 += 32) {
        __syncthreads();
        short8 va0 = *(const short8*)(agp + k0);
        short8 va1 = *(const short8*)(agp2 + k0);
        short8 vb  = *(const short8*)(bgp + k0);
        *(short8*)asw             = va0;
        *(short8*)(asw + 64 * 32) = va1;
        *(short8*)bsw             = vb;
        __syncthreads();
        short8 a0 = *(const short8*)ard0;
        short8 a1 = *(const short8*)ard1;
        #pragma unroll
        for (int ni = 0; ni < 4; ++ni) {
            short8 b = *(const short8*)(brd + ni * 16 * 32);
            acc[0][ni] = __builtin_amdgcn_mfma_f32_16x16x32_bf16(a0, b, acc[0][ni], 0, 0, 0);
            acc[1][ni] = __builtin_amdgcn_mfma_f32_16x16x32_bf16(a1, b, acc[1][ni], 0, 0, 0);
        }
    }

    #pragma unroll
    for (int mi = 0; mi < 2; ++mi) {
        #pragma unroll
        for (int ni = 0; ni < 4; ++ni) {
            int col = n0 + ni * 16 + lcol;
            float bv;
            if (EPI == 0) {
                // permuted-column layout: col = k*192 + h*32 + d
                int d = col & 31, hh = (col >> 5) % 6, k3 = col / 192;
                bv = bias[d * 18 + k3 * 6 + hh];
            } else {
                bv = bias[col];
            }
            #pragma unroll
            for (int t = 0; t < 4; ++t) {
                int row = m0 + w * 32 + mi * 16 + quad * 4 + t;
                float v = acc[mi][ni][t] + bv;
                if (EPI == 0) {
                    ((short*)outp)[(size_t)row * 576 + col] = f2bf(v);
                } else if (EPI == 1) {
                    int win = row / 49, p = row % 49;
                    int b = win >> 6, wm = (win >> 3) & 7, wwm = win & 7;
                    int hh = (p / 7) * 8 + wm, ww = (p % 7) * 8 + wwm;
                    ((float*)outp)[((size_t)b * (Hh * Wd) + hh * Wd + ww) * Cc + col] += v;
                } else if (EPI == 2) {
                    float gl = 0.5f * v * (1.0f + erff(v * 0.70710678118654752f));
                    ((short*)outp)[(size_t)row * HIDN + col] = f2bf(gl);
                } else {
                    ((float*)outp)[(size_t)row * Cc + col] += v;
                }
            }
        }
    }
}

// ---------------------------------------------------------------------------
// MFMA window attention: one wave (64 thr) per (window, head).
// qkvbuf column layout is [k*192 + h*32 + d] -> Q/K/V rows for a given
// (k,h) are 32 consecutive shorts (64B, 64B-aligned). Staging loads are
// short8, fully coalesced. LDS overlay: P reuses dead Q/K region.
// ---------------------------------------------------------------------------
__global__ void __launch_bounds__(64) k_attn(
    const short* __restrict__ C, short* __restrict__ aout)
{
    int h = blockIdx.x, win = blockIdx.y;
    int lane = threadIdx.x;
    int lcol = lane & 15, quad = lane >> 4;
    __shared__ __align__(16) short buf[7424];
    short* Q  = buf;            // [64*40]
    short* Kb = buf + 2560;     // [64*40]
    short* Vt = buf + 5120;     // [32*72]
    short* P  = buf;            // [64*72] overlays Q+Kb after S-phase

    const short8 z8 = {0, 0, 0, 0, 0, 0, 0, 0};
    const size_t wbase = (size_t)win * 49 * 576;
    const int hq = h * 32;
    const int pr = lane >> 2, d8 = (lane & 3) * 8;

    // Q and K: 16 rows per wave-iteration, 64B contiguous per row
    #pragma unroll
    for (int it = 0; it < 4; ++it) {
        int pp = pr + it * 16;
        bool ok = pp < 49;
        size_t ro = wbase + (size_t)(ok ? pp : 0) * 576 + hq + d8;
        short8 vq = ok ? *(const short8*)(C + ro)       : z8;
        short8 vk = ok ? *(const short8*)(C + ro + 192) : z8;
        *(short8*)(Q  + pp * 40 + d8) = vq;
        *(short8*)(Kb + pp * 40 + d8) = vk;
    }
    // V: coalesced row loads, transposed scatter into Vt[d][p]
    #pragma unroll
    for (int it = 0; it < 4; ++it) {
        int pp = pr + it * 16;
        bool ok = pp < 49;
        size_t ro = wbase + (size_t)(ok ? pp : 0) * 576 + 384 + hq + d8;
        short8 vv = ok ? *(const short8*)(C + ro) : z8;
        #pragma unroll
        for (int j = 0; j < 8; ++j)
            Vt[(d8 + j) * 72 + pp] = vv[j];
    }

    floatx4 s[4][4];
    #pragma unroll
    for (int mi = 0; mi < 4; ++mi) {
        short8 aq = *(const short8*)(Q + (mi * 16 + lcol) * 40 + quad * 8);
        #pragma unroll
        for (int ni = 0; ni < 4; ++ni) {
            short8 bk = *(const short8*)(Kb + (ni * 16 + lcol) * 40 + quad * 8);
            floatx4 z = {0, 0, 0, 0};
            s[mi][ni] = __builtin_amdgcn_mfma_f32_16x16x32_bf16(aq, bk, z, 0, 0, 0);
        }
    }

    const float scale = 0.17677669529663688f;   // 1/sqrt(32)
    #pragma unroll
    for (int mi = 0; mi < 4; ++mi) {
        #pragma unroll
        for (int reg = 0; reg < 4; ++reg) {
            float vv[4];
            float mx = -3e38f;
            #pragma unroll
            for (int ni = 0; ni < 4; ++ni) {
                int col = ni * 16 + lcol;
                float v = (col < 49) ? s[mi][ni][reg] * scale : -3e38f;
                vv[ni] = v;
                mx = fmaxf(mx, v);
            }
            #pragma unroll
            for (int off = 1; off < 16; off <<= 1)
                mx = fmaxf(mx, __shfl_xor(mx, off, 64));
            float sum = 0.f;
            #pragma unroll
            for (int ni = 0; ni < 4; ++ni) {
                int col = ni * 16 + lcol;
                float e = (col < 49) ? __expf(vv[ni] - mx) : 0.f;
                vv[ni] = e;
                sum += e;
            }
            #pragma unroll
            for (int off = 1; off < 16; off <<= 1)
                sum += __shfl_xor(sum, off, 64);
            float inv = 1.0f / sum;
            int row = mi * 16 + quad * 4 + reg;
            #pragma unroll
            for (int ni = 0; ni < 4; ++ni)
                P[row * 72 + ni * 16 + lcol] = f2bf(vv[ni] * inv);
        }
    }

    #pragma unroll
    for (int mi = 0; mi < 4; ++mi) {
        short8 a0 = *(const short8*)(P + (mi * 16 + lcol) * 72 + quad * 8);
        short8 a1 = *(const short8*)(P + (mi * 16 + lcol) * 72 + 32 + quad * 8);
        #pragma unroll
        for (int nd = 0; nd < 2; ++nd) {
            short8 b0 = *(const short8*)(Vt + (nd * 16 + lcol) * 72 + quad * 8);
            short8 b1 = *(const short8*)(Vt + (nd * 16 + lcol) * 72 + 32 + quad * 8);
            floatx4 z = {0, 0, 0, 0};
            floatx4 o = __builtin_amdgcn_mfma_f32_16x16x32_bf16(a0, b0, z, 0, 0, 0);
            o = __builtin_amdgcn_mfma_f32_16x16x32_bf16(a1, b1, o, 0, 0, 0);
            #pragma unroll
            for (int reg = 0; reg < 4; ++reg) {
                int row = mi * 16 + quad * 4 + reg;
                if (row < 49)
                    aout[((size_t)win * 49 + row) * Cc + h * HDim + nd * 16 + lcol] =
                        f2bf(o[reg]);
            }
        }
    }
}

// ---------------------------------------------------------------------------
extern "C" void kernel_launch(void* const* d_in, const int* in_sizes, int n_in,
                              void* d_out, int out_size, void* d_ws, size_t ws_size,
                              hipStream_t stream)
{
    (void)in_sizes; (void)n_in; (void)out_size; (void)ws_size;
    const float* x      = (const float*)d_in[0];
    const float* cpe0_w = (const float*)d_in[3];
    const float* cpe0_b = (const float*)d_in[4];
    const float* cpe1_w = (const float*)d_in[5];
    const float* cpe1_b = (const float*)d_in[6];
    const float* n1_g   = (const float*)d_in[7];
    const float* n1_b   = (const float*)d_in[8];
    const float* qkv_w  = (const float*)d_in[9];
    const float* qkv_b  = (const float*)d_in[10];
    const float* proj_w = (const float*)d_in[11];
    const float* proj_b = (const float*)d_in[12];
    const float* n2_g   = (const float*)d_in[13];
    const float* n2_b   = (const float*)d_in[14];
    const float* fc1_w  = (const float*)d_in[15];
    const float* fc1_b  = (const float*)d_in[16];
    const float* fc2_w  = (const float*)d_in[17];
    const float* fc2_b  = (const float*)d_in[18];
    float* out = (float*)d_out;

    char* ws = (char*)d_ws;
    float* shortcut = (float*)ws;                     // 77,070,336  (fp32 Tt*192)
    short* lnbuf    = (short*)(ws + 77070336);        // 38,535,168  (bf16 Tt*192)
    short* qkvbuf   = (short*)(ws + 115605504);       // 115,605,504 (bf16 Tt*576)
    short* attnout  = (short*)(ws + 231211008);       // 38,535,168
    short* h1       = qkvbuf;                         // overlays qkv+attn
    short* wqkvT    = (short*)(ws + 269746176);       // 221,184
    short* wprojT   = (short*)(ws + 269967360);       // 73,728
    short* wfc1T    = (short*)(ws + 270041088);       // 294,912
    short* wfc2T    = (short*)(ws + 270336000);       // 294,912

    k_transpose_qkv<<<dim3((192 * 576 + 255) / 256), dim3(256), 0, stream>>>(qkv_w, wqkvT);
    k_transpose<<<dim3((192 * 192 + 255) / 256), dim3(256), 0, stream>>>(proj_w, wprojT, 192, 192);
    k_transpose<<<dim3((192 * 768 + 255) / 256), dim3(256), 0, stream>>>(fc1_w, wfc1T, 192, 768);
    k_transpose<<<dim3((768 * 192 + 255) / 256), dim3(256), 0, stream>>>(fc2_w, wfc2T, 768, 192);

    k_cpe_ln<<<dim3(Tt / (4 * CPE_TPW)), dim3(256), 0, stream>>>(x, cpe0_w, cpe0_b, n1_g, n1_b,
                                                                 shortcut, lnbuf, 1);
    k_gemm_tiled<192, 0><<<dim3(9, Tt / 128), dim3(256), 0, stream>>>(lnbuf, wqkvT, qkv_b, qkvbuf);
    k_attn<<<dim3(NHh, NWIN), dim3(64), 0, stream>>>(qkvbuf, attnout);
    k_gemm_tiled<192, 1><<<dim3(3, Tt / 128), dim3(256), 0, stream>>>(attnout, wprojT, proj_b, shortcut);
    k_cpe_ln<<<dim3(Tt / (4 * CPE_TPW)), dim3(256), 0, stream>>>(shortcut, cpe1_w, cpe1_b, n2_g, n2_b,
                                                                 out, lnbuf, 0);
    k_gemm_tiled<192, 2><<<dim3(12, Tt / 128), dim3(256), 0, stream>>>(lnbuf, wfc1T, fc1_b, h1);
    k_gemm_tiled<768, 3><<<dim3(3, Tt / 128), dim3(256), 0, stream>>>(h1, wfc2T, fc2_b, out);
}

// Round 5
// 598.967 us; speedup vs baseline: 1.7157x; 1.1777x over previous
//
#include <hip/hip_runtime.h>
#include <hip/hip_bf16.h>
#include <math.h>

// Problem constants
#define Bn   32
#define Hh   56
#define Wd   56
#define Cc   192
#define NHh  6
#define HDim 32
#define HIDN 768
#define Tt   (Bn*Hh*Wd)          // 100352 tokens
#define NWIN (Bn*64)             // 2048 windows

typedef __attribute__((ext_vector_type(8))) short short8;
typedef __attribute__((ext_vector_type(4))) short s4v;
typedef __attribute__((ext_vector_type(4))) float floatx4;

__device__ __forceinline__ short f2bf(float f) {
    unsigned u = __float_as_uint(f);
    u += 0x7fffu + ((u >> 16) & 1u);     // round-to-nearest-even
    return (short)(u >> 16);
}
__device__ __forceinline__ float bf2f(short s) {
    return __uint_as_float(((unsigned)(unsigned short)s) << 16);
}

// XCD-aware bijective block swizzle (requires nb % 8 == 0): each XCD gets a
// contiguous chunk of the flat block range -> neighbor blocks share an L2.
__device__ __forceinline__ int xcd_swz(int bid, int nb) {
    return (bid & 7) * (nb >> 3) + (bid >> 3);
}

// ---------------------------------------------------------------------------
// Weight transpose + bf16 convert: W[K,N] fp32 -> WT[N,K] bf16
// ---------------------------------------------------------------------------
__global__ void k_transpose(const float* __restrict__ W, short* __restrict__ WT,
                            int K, int N) {
    int idx = blockIdx.x * 256 + threadIdx.x;
    if (idx >= K * N) return;
    int n = idx / K, k = idx % K;        // coalesced writes
    WT[idx] = f2bf(W[k * N + n]);
}

// ---------------------------------------------------------------------------
// QKV weight transpose with COLUMN PERMUTATION:
// reference column order is (d k h): col = d*18 + k*6 + h.
// We emit new order col' = k*192 + h*32 + d so the GEMM writes qkvbuf in a
// per-(k,head) contiguous-d layout -> attention loads become coalesced 64B rows.
// ---------------------------------------------------------------------------
__global__ void k_transpose_qkv(const float* __restrict__ W, short* __restrict__ WT) {
    int idx = blockIdx.x * 256 + threadIdx.x;
    if (idx >= 192 * 576) return;
    int n = idx / 192, kk = idx % 192;           // n = new col, kk = K row
    int d = n & 31, hh = (n >> 5) % 6, k3 = n / 192;
    int oc = d * 18 + k3 * 6 + hh;               // original column
    WT[idx] = f2bf(W[kk * 576 + oc]);
}

// ---------------------------------------------------------------------------
// Fused depthwise-3x3 CPE (residual) + LayerNorm — branchless sliding window.
// One wave owns 8 consecutive tokens along w (Wd = 7*8). It loads the full
// 3x10 float4 halo window with CLAMPED addresses (30 independent loads, all
// in flight at once), applies edge zero-masks in registers (== zero-pad conv),
// then does pure-register stencil FMAs and 8 interleaved shfl reductions.
// No branches around loads -> one memory latency per wave, not 30.
// ---------------------------------------------------------------------------
__global__ void __launch_bounds__(256) k_cpe_ln(
    const float* __restrict__ xin, const float* __restrict__ wconv,
    const float* __restrict__ bconv, const float* __restrict__ g,
    const float* __restrict__ beta, float* __restrict__ ysum_out,
    short* __restrict__ ln_out, int windowed)
{
    const int lane = threadIdx.x & 63;
    const int wv   = threadIdx.x >> 6;
    const bool act = lane < 48;
    const int c4   = (lane < 48 ? lane : lane - 16) * 4;   // clamped channel base

    const floatx4 zf = {0.f, 0.f, 0.f, 0.f};
    float wreg[36];
    #pragma unroll
    for (int i = 0; i < 9; ++i)
        *(floatx4*)&wreg[i * 4] = *(const floatx4*)(wconv + c4 * 9 + i * 4);
    const floatx4 gv  = *(const floatx4*)(g + c4);
    const floatx4 bv  = *(const floatx4*)(beta + c4);
    const floatx4 bcv = *(const floatx4*)(bconv + c4);

    // wave -> (b, h, w0): 8-token run along w
    const int W = xcd_swz(blockIdx.x, gridDim.x) * 4 + wv;
    const int b = W / (Hh * 7);
    const int rem = W % (Hh * 7);
    const int h = rem / 7, wslot = rem % 7;
    const int w0 = wslot * 8;

    // ---- load 3x10 halo window, clamped addresses, zero branches ----
    floatx4 r[3][10];
    const int hy0 = (h > 0) ? h - 1 : 0;
    const int hy2 = (h < Hh - 1) ? h + 1 : Hh - 1;
    const int hys[3] = {hy0, h, hy2};
    #pragma unroll
    for (int dy = 0; dy < 3; ++dy) {
        const float* rp = xin + ((size_t)b * (Hh * Wd) + hys[dy] * Wd) * Cc + c4;
        #pragma unroll
        for (int j = 0; j < 10; ++j) {
            int wx = w0 - 1 + j;
            int wc = (wx < 0) ? 0 : ((wx > Wd - 1) ? Wd - 1 : wx);
            r[dy][j] = *(const floatx4*)(rp + wc * Cc);
        }
    }
    // edge masks (wave-uniform, register-only)
    if (h == 0) {
        #pragma unroll
        for (int j = 0; j < 10; ++j) r[0][j] = zf;
    }
    if (h == Hh - 1) {
        #pragma unroll
        for (int j = 0; j < 10; ++j) r[2][j] = zf;
    }
    if (w0 == 0)      { r[0][0] = zf; r[1][0] = zf; r[2][0] = zf; }
    if (w0 == Wd - 8) { r[0][9] = zf; r[1][9] = zf; r[2][9] = zf; }

    // ---- stencil: 8 tokens, pure register FMAs ----
    floatx4 val[8];
    #pragma unroll
    for (int tk = 0; tk < 8; ++tk) {
        floatx4 a = bcv;
        #pragma unroll
        for (int dy = 0; dy < 3; ++dy) {
            #pragma unroll
            for (int dx = 0; dx < 3; ++dx) {
                const int t = dy * 3 + dx;
                floatx4 v = r[dy][tk + dx];
                #pragma unroll
                for (int j = 0; j < 4; ++j)
                    a[j] += wreg[j * 9 + t] * v[j];
            }
        }
        floatx4 xc = r[1][tk + 1];               // center (residual input)
        #pragma unroll
        for (int j = 0; j < 4; ++j) val[tk][j] = xc[j] + a[j];
    }

    // ---- 8 interleaved LN reductions (lanes 48-63 contribute zero) ----
    float s[8], s2[8];
    #pragma unroll
    for (int tk = 0; tk < 8; ++tk) {
        float a = val[tk][0] + val[tk][1] + val[tk][2] + val[tk][3];
        float a2 = val[tk][0]*val[tk][0] + val[tk][1]*val[tk][1]
                 + val[tk][2]*val[tk][2] + val[tk][3]*val[tk][3];
        s[tk]  = act ? a  : 0.f;
        s2[tk] = act ? a2 : 0.f;
    }
    #pragma unroll
    for (int off = 1; off < 64; off <<= 1) {
        #pragma unroll
        for (int tk = 0; tk < 8; ++tk) {
            s[tk]  += __shfl_xor(s[tk],  off, 64);
            s2[tk] += __shfl_xor(s2[tk], off, 64);
        }
    }

    // ---- epilogue: residual store + LN bf16 store ----
    const int blk0 = (b * Hh + h) * Wd + w0;
    #pragma unroll
    for (int tk = 0; tk < 8; ++tk) {
        const float mean = s[tk] * (1.0f / Cc);
        const float var  = s2[tk] * (1.0f / Cc) - mean * mean;
        const float rs   = rsqrtf(var + 1e-5f);
        int rr;
        if (windowed) {
            int win = b * 64 + (h & 7) * 8 + tk;     // (w0+tk)&7 == tk
            int pos = (h >> 3) * 7 + wslot;          // (w0+tk)>>3 == wslot
            rr = win * 49 + pos;
        } else {
            rr = blk0 + tk;
        }
        if (act) {
            *(floatx4*)(ysum_out + (size_t)(blk0 + tk) * Cc + c4) = val[tk];
            s4v o;
            #pragma unroll
            for (int j = 0; j < 4; ++j)
                o[j] = f2bf((val[tk][j] - mean) * rs * gv[j] + bv[j]);
            *(s4v*)(ln_out + (size_t)rr * Cc + c4) = o;
        }
    }
}

// ---------------------------------------------------------------------------
// Tiled MFMA GEMM (m93-style): BM=128, BN=64, BK=32, 256 thr / 4 waves.
// XCD-chunked flat-block swizzle: the gx n-tiles sharing one A-panel stay on
// one XCD (A-panel L2 reuse).
// EPI==0: qkv output (bf16, permuted-column bias remap)
// EPI==1: proj output un-windowed, += into fp32 shortcut
// EPI==2: fc1 + exact GELU, bf16
// EPI==3: fc2, += into fp32 out
// ---------------------------------------------------------------------------
template<int K, int EPI>
__global__ void __launch_bounds__(256) k_gemm_tiled(
    const short* __restrict__ A, const short* __restrict__ BT,
    const float* __restrict__ bias, void* __restrict__ outp)
{
    __shared__ __align__(16) short As[128 * 32];
    __shared__ __align__(16) short Bs[64 * 32];
    const int tid = threadIdx.x;
    const int gx = gridDim.x;
    const int flat = blockIdx.y * gx + blockIdx.x;
    const int swz = xcd_swz(flat, gx * gridDim.y);
    const int n0 = (swz % gx) * 64;
    const int m0 = (swz / gx) * 128;
    const int w = tid >> 6, lane = tid & 63;
    const int lcol = lane & 15, quad = lane >> 4;

    floatx4 acc[2][4];
    #pragma unroll
    for (int mi = 0; mi < 2; ++mi)
        #pragma unroll
        for (int ni = 0; ni < 4; ++ni) acc[mi][ni] = (floatx4){0, 0, 0, 0};

    const int ar = tid >> 2, ac = (tid & 3) * 8;
    const short* agp  = A + (size_t)(m0 + ar) * K + ac;
    const short* agp2 = A + (size_t)(m0 + 64 + ar) * K + ac;
    const short* bgp  = BT + (size_t)(n0 + ar) * K + ac;
    short* asw = As + tid * 8;
    short* bsw = Bs + tid * 8;

    const short* ard0 = As + (w * 32 + lcol) * 32 + quad * 8;
    const short* ard1 = As + (w * 32 + 16 + lcol) * 32 + quad * 8;
    const short* brd  = Bs + lcol * 32 + quad * 8;

    for (int k0 = 0; k0 < K; k0 += 32) {
        __syncthreads();
        short8 va0 = *(const short8*)(agp + k0);
        short8 va1 = *(const short8*)(agp2 + k0);
        short8 vb  = *(const short8*)(bgp + k0);
        *(short8*)asw             = va0;
        *(short8*)(asw + 64 * 32) = va1;
        *(short8*)bsw             = vb;
        __syncthreads();
        short8 a0 = *(const short8*)ard0;
        short8 a1 = *(const short8*)ard1;
        #pragma unroll
        for (int ni = 0; ni < 4; ++ni) {
            short8 b = *(const short8*)(brd + ni * 16 * 32);
            acc[0][ni] = __builtin_amdgcn_mfma_f32_16x16x32_bf16(a0, b, acc[0][ni], 0, 0, 0);
            acc[1][ni] = __builtin_amdgcn_mfma_f32_16x16x32_bf16(a1, b, acc[1][ni], 0, 0, 0);
        }
    }

    #pragma unroll
    for (int mi = 0; mi < 2; ++mi) {
        #pragma unroll
        for (int ni = 0; ni < 4; ++ni) {
            int col = n0 + ni * 16 + lcol;
            float bv;
            if (EPI == 0) {
                // permuted-column layout: col = k*192 + h*32 + d
                int d = col & 31, hh = (col >> 5) % 6, k3 = col / 192;
                bv = bias[d * 18 + k3 * 6 + hh];
            } else {
                bv = bias[col];
            }
            #pragma unroll
            for (int t = 0; t < 4; ++t) {
                int row = m0 + w * 32 + mi * 16 + quad * 4 + t;
                float v = acc[mi][ni][t] + bv;
                if (EPI == 0) {
                    ((short*)outp)[(size_t)row * 576 + col] = f2bf(v);
                } else if (EPI == 1) {
                    int win = row / 49, p = row % 49;
                    int b = win >> 6, wm = (win >> 3) & 7, wwm = win & 7;
                    int hh = (p / 7) * 8 + wm, ww = (p % 7) * 8 + wwm;
                    ((float*)outp)[((size_t)b * (Hh * Wd) + hh * Wd + ww) * Cc + col] += v;
                } else if (EPI == 2) {
                    float gl = 0.5f * v * (1.0f + erff(v * 0.70710678118654752f));
                    ((short*)outp)[(size_t)row * HIDN + col] = f2bf(gl);
                } else {
                    ((float*)outp)[(size_t)row * Cc + col] += v;
                }
            }
        }
    }
}

// ---------------------------------------------------------------------------
// MFMA window attention: one wave (64 thr) per (window, head).
// qkvbuf column layout is [k*192 + h*32 + d] -> Q/K/V rows for a given
// (k,h) are 32 consecutive shorts (64B, 64B-aligned). Staging loads are
// short8, fully coalesced. LDS overlay: P reuses dead Q/K region.
// ---------------------------------------------------------------------------
__global__ void __launch_bounds__(64) k_attn(
    const short* __restrict__ C, short* __restrict__ aout)
{
    int h = blockIdx.x, win = blockIdx.y;
    int lane = threadIdx.x;
    int lcol = lane & 15, quad = lane >> 4;
    __shared__ __align__(16) short buf[7424];
    short* Q  = buf;            // [64*40]
    short* Kb = buf + 2560;     // [64*40]
    short* Vt = buf + 5120;     // [32*72]
    short* P  = buf;            // [64*72] overlays Q+Kb after S-phase

    const short8 z8 = {0, 0, 0, 0, 0, 0, 0, 0};
    const size_t wbase = (size_t)win * 49 * 576;
    const int hq = h * 32;
    const int pr = lane >> 2, d8 = (lane & 3) * 8;

    // Q and K: 16 rows per wave-iteration, 64B contiguous per row
    #pragma unroll
    for (int it = 0; it < 4; ++it) {
        int pp = pr + it * 16;
        bool ok = pp < 49;
        size_t ro = wbase + (size_t)(ok ? pp : 0) * 576 + hq + d8;
        short8 vq = ok ? *(const short8*)(C + ro)       : z8;
        short8 vk = ok ? *(const short8*)(C + ro + 192) : z8;
        *(short8*)(Q  + pp * 40 + d8) = vq;
        *(short8*)(Kb + pp * 40 + d8) = vk;
    }
    // V: coalesced row loads, transposed scatter into Vt[d][p]
    #pragma unroll
    for (int it = 0; it < 4; ++it) {
        int pp = pr + it * 16;
        bool ok = pp < 49;
        size_t ro = wbase + (size_t)(ok ? pp : 0) * 576 + 384 + hq + d8;
        short8 vv = ok ? *(const short8*)(C + ro) : z8;
        #pragma unroll
        for (int j = 0; j < 8; ++j)
            Vt[(d8 + j) * 72 + pp] = vv[j];
    }

    floatx4 s[4][4];
    #pragma unroll
    for (int mi = 0; mi < 4; ++mi) {
        short8 aq = *(const short8*)(Q + (mi * 16 + lcol) * 40 + quad * 8);
        #pragma unroll
        for (int ni = 0; ni < 4; ++ni) {
            short8 bk = *(const short8*)(Kb + (ni * 16 + lcol) * 40 + quad * 8);
            floatx4 z = {0, 0, 0, 0};
            s[mi][ni] = __builtin_amdgcn_mfma_f32_16x16x32_bf16(aq, bk, z, 0, 0, 0);
        }
    }

    const float scale = 0.17677669529663688f;   // 1/sqrt(32)
    #pragma unroll
    for (int mi = 0; mi < 4; ++mi) {
        #pragma unroll
        for (int reg = 0; reg < 4; ++reg) {
            float vv[4];
            float mx = -3e38f;
            #pragma unroll
            for (int ni = 0; ni < 4; ++ni) {
                int col = ni * 16 + lcol;
                float v = (col < 49) ? s[mi][ni][reg] * scale : -3e38f;
                vv[ni] = v;
                mx = fmaxf(mx, v);
            }
            #pragma unroll
            for (int off = 1; off < 16; off <<= 1)
                mx = fmaxf(mx, __shfl_xor(mx, off, 64));
            float sum = 0.f;
            #pragma unroll
            for (int ni = 0; ni < 4; ++ni) {
                int col = ni * 16 + lcol;
                float e = (col < 49) ? __expf(vv[ni] - mx) : 0.f;
                vv[ni] = e;
                sum += e;
            }
            #pragma unroll
            for (int off = 1; off < 16; off <<= 1)
                sum += __shfl_xor(sum, off, 64);
            float inv = 1.0f / sum;
            int row = mi * 16 + quad * 4 + reg;
            #pragma unroll
            for (int ni = 0; ni < 4; ++ni)
                P[row * 72 + ni * 16 + lcol] = f2bf(vv[ni] * inv);
        }
    }

    #pragma unroll
    for (int mi = 0; mi < 4; ++mi) {
        short8 a0 = *(const short8*)(P + (mi * 16 + lcol) * 72 + quad * 8);
        short8 a1 = *(const short8*)(P + (mi * 16 + lcol) * 72 + 32 + quad * 8);
        #pragma unroll
        for (int nd = 0; nd < 2; ++nd) {
            short8 b0 = *(const short8*)(Vt + (nd * 16 + lcol) * 72 + quad * 8);
            short8 b1 = *(const short8*)(Vt + (nd * 16 + lcol) * 72 + 32 + quad * 8);
            floatx4 z = {0, 0, 0, 0};
            floatx4 o = __builtin_amdgcn_mfma_f32_16x16x32_bf16(a0, b0, z, 0, 0, 0);
            o = __builtin_amdgcn_mfma_f32_16x16x32_bf16(a1, b1, o, 0, 0, 0);
            #pragma unroll
            for (int reg = 0; reg < 4; ++reg) {
                int row = mi * 16 + quad * 4 + reg;
                if (row < 49)
                    aout[((size_t)win * 49 + row) * Cc + h * HDim + nd * 16 + lcol] =
                        f2bf(o[reg]);
            }
        }
    }
}

// ---------------------------------------------------------------------------
extern "C" void kernel_launch(void* const* d_in, const int* in_sizes, int n_in,
                              void* d_out, int out_size, void* d_ws, size_t ws_size,
                              hipStream_t stream)
{
    (void)in_sizes; (void)n_in; (void)out_size; (void)ws_size;
    const float* x      = (const float*)d_in[0];
    const float* cpe0_w = (const float*)d_in[3];
    const float* cpe0_b = (const float*)d_in[4];
    const float* cpe1_w = (const float*)d_in[5];
    const float* cpe1_b = (const float*)d_in[6];
    const float* n1_g   = (const float*)d_in[7];
    const float* n1_b   = (const float*)d_in[8];
    const float* qkv_w  = (const float*)d_in[9];
    const float* qkv_b  = (const float*)d_in[10];
    const float* proj_w = (const float*)d_in[11];
    const float* proj_b = (const float*)d_in[12];
    const float* n2_g   = (const float*)d_in[13];
    const float* n2_b   = (const float*)d_in[14];
    const float* fc1_w  = (const float*)d_in[15];
    const float* fc1_b  = (const float*)d_in[16];
    const float* fc2_w  = (const float*)d_in[17];
    const float* fc2_b  = (const float*)d_in[18];
    float* out = (float*)d_out;

    char* ws = (char*)d_ws;
    float* shortcut = (float*)ws;                     // 77,070,336  (fp32 Tt*192)
    short* lnbuf    = (short*)(ws + 77070336);        // 38,535,168  (bf16 Tt*192)
    short* qkvbuf   = (short*)(ws + 115605504);       // 115,605,504 (bf16 Tt*576)
    short* attnout  = (short*)(ws + 231211008);       // 38,535,168
    short* h1       = qkvbuf;                         // overlays qkv+attn
    short* wqkvT    = (short*)(ws + 269746176);       // 221,184
    short* wprojT   = (short*)(ws + 269967360);       // 73,728
    short* wfc1T    = (short*)(ws + 270041088);       // 294,912
    short* wfc2T    = (short*)(ws + 270336000);       // 294,912

    k_transpose_qkv<<<dim3((192 * 576 + 255) / 256), dim3(256), 0, stream>>>(qkv_w, wqkvT);
    k_transpose<<<dim3((192 * 192 + 255) / 256), dim3(256), 0, stream>>>(proj_w, wprojT, 192, 192);
    k_transpose<<<dim3((192 * 768 + 255) / 256), dim3(256), 0, stream>>>(fc1_w, wfc1T, 192, 768);
    k_transpose<<<dim3((768 * 192 + 255) / 256), dim3(256), 0, stream>>>(fc2_w, wfc2T, 768, 192);

    k_cpe_ln<<<dim3(Tt / 32), dim3(256), 0, stream>>>(x, cpe0_w, cpe0_b, n1_g, n1_b,
                                                      shortcut, lnbuf, 1);
    k_gemm_tiled<192, 0><<<dim3(9, Tt / 128), dim3(256), 0, stream>>>(lnbuf, wqkvT, qkv_b, qkvbuf);
    k_attn<<<dim3(NHh, NWIN), dim3(64), 0, stream>>>(qkvbuf, attnout);
    k_gemm_tiled<192, 1><<<dim3(3, Tt / 128), dim3(256), 0, stream>>>(attnout, wprojT, proj_b, shortcut);
    k_cpe_ln<<<dim3(Tt / 32), dim3(256), 0, stream>>>(shortcut, cpe1_w, cpe1_b, n2_g, n2_b,
                                                      out, lnbuf, 0);
    k_gemm_tiled<192, 2><<<dim3(12, Tt / 128), dim3(256), 0, stream>>>(lnbuf, wfc1T, fc1_b, h1);
    k_gemm_tiled<768, 3><<<dim3(3, Tt / 128), dim3(256), 0, stream>>>(h1, wfc2T, fc2_b, out);
}